// Round 4
// baseline (85.501 us; speedup 1.0000x reference)
//
#include <hip/hip_runtime.h>
#include <math.h>

#define TPB  256   // threads per block
#define NP   20    // bone pairs
#define ROW  63    // floats per batch elem (21*3)
#define RPC  64    // rows per chunk
#define TPR  4     // threads cooperating per row
#define PPT  5     // pairs per thread
#define NBLK 1024  // grid size (persistent, 4 blocks/CU)

typedef __attribute__((address_space(3))) unsigned int lds_u32;
typedef __attribute__((address_space(1))) const unsigned int glb_u32;

__device__ __forceinline__ void gload16(const void* g, void* l) {
    // async global->LDS, 16B per lane; LDS dest = wave-uniform base + lane*16
    __builtin_amdgcn_global_load_lds((glb_u32*)g, (lds_u32*)l, 16, 0, 0);
}

__global__ __launch_bounds__(TPB, 4) void angle_fused(
    const float* __restrict__ pred, const float* __restrict__ gt,
    float* __restrict__ partial, unsigned* __restrict__ counter,
    float* __restrict__ out, int nchunks, double inv)
{
    // HANDS17 pairs
    constexpr int I0[NP] = {0,0,0,0,0,1,6,7,2,9,10,3,12,13,4,15,16,5,18,19};
    constexpr int I1[NP] = {1,2,3,4,5,6,7,8,9,10,11,12,13,14,15,16,17,18,19,20};

    __shared__ __align__(16) float s[2 * RPC * ROW];   // 32256 B: pred | gt
    __shared__ float wsum[TPB / 64];
    __shared__ double dsum[TPB / 64];
    __shared__ bool isLast;

    const int t = threadIdx.x;
    const int lane = t & 63;
    const int wv = t >> 6;
    const int p0 = (t & (TPR - 1)) * PPT;
    const float* rowp = s + (t >> 2) * ROW;
    const float* rowg = s + RPC * ROW + (t >> 2) * ROW;

    constexpr int NV = RPC * ROW / 4;     // 1008 float4 per tensor
    float4* s4 = (float4*)s;

    float sum = 0.0f;

    for (int c = blockIdx.x; c < nchunks; c += gridDim.x) {
        const size_t base = (size_t)c * RPC * ROW;
        const float4* p4 = (const float4*)(pred + base);  // 16128B chunks, 16B-aligned
        const float4* g4 = (const float4*)(gt + base);

        // ---- stage BOTH tensors async into LDS (8 dwordx4 in flight/wave) ----
        #pragma unroll
        for (int k = 0; k < (NV + TPB - 1) / TPB; ++k) {
            const int wb = k * TPB + wv * 64;   // wave-uniform float4 index
            if (wb + lane < NV) {
                gload16(p4 + wb + lane, s4 + wb);
                gload16(g4 + wb + lane, s4 + NV + wb);
            }
        }
        __syncthreads();   // drains vmcnt before barrier

        #pragma unroll
        for (int p = 0; p < PPT; ++p) {
            const int a = I0[p0 + p] * 3, b = I1[p0 + p] * 3;
            float v1u = rowp[a]     - rowp[b];
            float v1v = rowp[a + 1] - rowp[b + 1];
            float v2u = rowg[a]     - rowg[b];
            float v2v = rowg[a + 1] - rowg[b + 1];
            float dot = v1u * v2u + v1v * v2v;
            float m1  = v1u * v1u + v1v * v1v;
            float m2  = v2u * v2u + v2v * v2v;
            sum += 1.0f - fabsf(dot) / sqrtf(m1 * m2);
        }
        __syncthreads();   // protect s before next chunk's staging
    }

    // ---- block reduction (deterministic) ----
    #pragma unroll
    for (int off = 32; off > 0; off >>= 1) sum += __shfl_down(sum, off, 64);
    if (lane == 0) wsum[wv] = sum;
    __syncthreads();
    if (t == 0) {
        float bs = 0.0f;
        #pragma unroll
        for (int w = 0; w < TPB / 64; ++w) bs += wsum[w];
        partial[blockIdx.x] = bs;
        __threadfence();                       // release partial (device scope)
        unsigned v = atomicAdd(counter, 1u);   // device-scope ticket
        isLast = (v == (unsigned)(gridDim.x - 1));
    }
    __syncthreads();

    // ---- last-done block performs the final reduction (fixed order -> deterministic) ----
    if (isLast) {
        __threadfence();                       // acquire all partials
        double s2 = 0.0;
        const volatile float* vp = partial;
        for (int i = t; i < NBLK; i += TPB) s2 += (double)vp[i];
        #pragma unroll
        for (int off = 32; off > 0; off >>= 1) s2 += __shfl_down(s2, off, 64);
        if (lane == 0) dsum[wv] = s2;
        __syncthreads();
        if (t == 0) {
            double tot = dsum[0] + dsum[1] + dsum[2] + dsum[3];
            out[0] = (float)(tot * inv);
        }
    }
}

extern "C" void kernel_launch(void* const* d_in, const int* in_sizes, int n_in,
                              void* d_out, int out_size, void* d_ws, size_t ws_size,
                              hipStream_t stream) {
    const float* pred = (const float*)d_in[0];
    const float* gt   = (const float*)d_in[1];
    float* out        = (float*)d_out;
    float* partial    = (float*)d_ws;
    unsigned* counter = (unsigned*)((char*)d_ws + NBLK * sizeof(float));

    const int B = in_sizes[0] / ROW;          // 524288
    const int nchunks = B / RPC;              // 8192

    // counter must be 0 at each launch (d_ws is poisoned 0xAA once, never restored)
    hipMemsetAsync(counter, 0, sizeof(unsigned), stream);

    const double inv = 1.0 / ((double)B * (double)NP);
    angle_fused<<<NBLK, TPB, 0, stream>>>(pred, gt, partial, counter, out, nchunks, inv);
}

// Round 5
// 47.663 us; speedup vs baseline: 1.7939x; 1.7939x over previous
//
#include <hip/hip_runtime.h>
#include <math.h>

#define TPB 256   // threads per block
#define NP  20    // bone pairs
#define ROW 63    // floats per batch elem (21*3)
#define RPC 64    // rows per chunk
#define TPR 4     // threads cooperating per row
#define PPT 5     // pairs per thread

typedef __attribute__((address_space(3))) unsigned int lds_u32;
typedef __attribute__((address_space(1))) const unsigned int glb_u32;

__device__ __forceinline__ void gload16(const void* g, void* l) {
    // async global->LDS, 16B per lane; LDS dest = wave-uniform base + lane*16
    __builtin_amdgcn_global_load_lds((glb_u32*)g, (lds_u32*)l, 16, 0, 0);
}

__global__ __launch_bounds__(TPB, 4) void angle_partial(
    const float* __restrict__ pred, const float* __restrict__ gt,
    float* __restrict__ partial, int nchunks)
{
    // HANDS17 pairs
    constexpr int I0[NP] = {0,0,0,0,0,1,6,7,2,9,10,3,12,13,4,15,16,5,18,19};
    constexpr int I1[NP] = {1,2,3,4,5,6,7,8,9,10,11,12,13,14,15,16,17,18,19,20};

    __shared__ __align__(16) float s[2 * RPC * ROW];   // 32256 B: pred | gt
    __shared__ float wsum[TPB / 64];

    const int t = threadIdx.x;
    const int lane = t & 63;
    const int wv = t >> 6;
    const int p0 = (t & (TPR - 1)) * PPT;
    const float* rowp = s + (t >> 2) * ROW;
    const float* rowg = s + RPC * ROW + (t >> 2) * ROW;

    constexpr int NV = RPC * ROW / 4;     // 1008 float4 per tensor
    float4* s4 = (float4*)s;

    float sum = 0.0f;

    for (int c = blockIdx.x; c < nchunks; c += gridDim.x) {
        const size_t base = (size_t)c * RPC * ROW;
        const float4* p4 = (const float4*)(pred + base);  // 16128B chunks, 16B-aligned
        const float4* g4 = (const float4*)(gt + base);

        // ---- stage BOTH tensors async into LDS (8 dwordx4 in flight/wave) ----
        #pragma unroll
        for (int k = 0; k < (NV + TPB - 1) / TPB; ++k) {
            const int wb = k * TPB + wv * 64;   // wave-uniform float4 index
            if (wb + lane < NV) {
                gload16(p4 + wb + lane, s4 + wb);
                gload16(g4 + wb + lane, s4 + NV + wb);
            }
        }
        __syncthreads();   // drains vmcnt before barrier

        #pragma unroll
        for (int p = 0; p < PPT; ++p) {
            const int a = I0[p0 + p] * 3, b = I1[p0 + p] * 3;
            float v1u = rowp[a]     - rowp[b];
            float v1v = rowp[a + 1] - rowp[b + 1];
            float v2u = rowg[a]     - rowg[b];
            float v2v = rowg[a + 1] - rowg[b + 1];
            float dot = v1u * v2u + v1v * v2v;
            float m1  = v1u * v1u + v1v * v1v;
            float m2  = v2u * v2u + v2v * v2v;
            sum += 1.0f - fabsf(dot) / sqrtf(m1 * m2);
        }
        __syncthreads();   // protect s before next chunk's staging
    }

    // ---- block reduction (deterministic) ----
    #pragma unroll
    for (int off = 32; off > 0; off >>= 1) sum += __shfl_down(sum, off, 64);
    if (lane == 0) wsum[wv] = sum;
    __syncthreads();
    if (t == 0) {
        float bs = 0.0f;
        #pragma unroll
        for (int w = 0; w < TPB / 64; ++w) bs += wsum[w];
        partial[blockIdx.x] = bs;
    }
}

__global__ __launch_bounds__(256) void angle_final(
    const float* __restrict__ partial, int n, float* __restrict__ out, double inv)
{
    const int t = threadIdx.x;
    double sum = 0.0;
    for (int i = t; i < n; i += 256) sum += (double)partial[i];
    #pragma unroll
    for (int off = 32; off > 0; off >>= 1) sum += __shfl_down(sum, off, 64);
    __shared__ double ws[4];
    if ((t & 63) == 0) ws[t >> 6] = sum;
    __syncthreads();
    if (t == 0) {
        double tot = ws[0] + ws[1] + ws[2] + ws[3];
        out[0] = (float)(tot * inv);
    }
}

extern "C" void kernel_launch(void* const* d_in, const int* in_sizes, int n_in,
                              void* d_out, int out_size, void* d_ws, size_t ws_size,
                              hipStream_t stream) {
    const float* pred = (const float*)d_in[0];
    const float* gt   = (const float*)d_in[1];
    float* out        = (float*)d_out;
    float* partial    = (float*)d_ws;

    const int B = in_sizes[0] / ROW;          // 524288
    const int nchunks = B / RPC;              // 8192
    const int nblocks = 1024;                 // 256 CU x 4 resident blocks (LDS-capped)

    angle_partial<<<nblocks, TPB, 0, stream>>>(pred, gt, partial, nchunks);

    const double inv = 1.0 / ((double)B * (double)NP);
    angle_final<<<1, 256, 0, stream>>>(partial, nblocks, out, inv);
}